// Round 1
// baseline (215.712 us; speedup 1.0000x reference)
//
#include <hip/hip_runtime.h>
#include <math.h>

#define L 16384
#define H 128
#define P 256
#define CL 64
#define NCH (L/CL)

struct Params { float M11,M12,M21,M22,s1,s2; };

__device__ inline Params get_params(const float* A_diag, const float* steps, int p){
  float A = A_diag[p]; A = A > 0.f ? A : 0.f;          // relu
  float dt = 1.f/(1.f + expf(-steps[p]));              // sigmoid
  float schur = 1.f/(1.f + dt*dt*A);
  Params q;
  q.M11 = 1.f - dt*dt*A*schur;
  q.M12 = -dt*A*schur;
  q.M21 = dt*schur;
  q.M22 = schur;
  q.s1 = q.M11*dt;   // F1 = M11*dt*Bu
  q.s2 = q.M21*dt;   // F2 = M21*dt*Bu
  return q;
}

// ---------------- Kernel 1: Bu = input @ Bc.T (re & im planes) ----------------
// block: 256 threads = p; each block does 32 rows of l. LDS holds input tile.
__global__ __launch_bounds__(256) void bu_gemm(const float* __restrict__ in,
                                               const float* __restrict__ B,
                                               float* __restrict__ BuRe,
                                               float* __restrict__ BuIm){
  __shared__ float4 stile[32][32];                     // 32 l-rows x 128 h (as float4)
  int l0 = blockIdx.x * 32;
  const float4* gin4 = (const float4*)(in + (size_t)l0*H);
  for (int i = threadIdx.x; i < 32*32; i += 256) stile[i>>5][i&31] = gin4[i];
  __syncthreads();
  int p = threadIdx.x;
  const float4* B4 = (const float4*)(B + (size_t)p*H*2); // B[p][h][{re,im}] -> 64 float4
  float2 acc[32];
  #pragma unroll
  for (int r=0;r<32;r++) acc[r] = make_float2(0.f,0.f);
  for (int h4=0; h4<32; h4++){
    float4 b0 = B4[h4*2];       // h=4h4:   re,im ; h=4h4+1: re,im
    float4 b1 = B4[h4*2+1];     // h=4h4+2, 4h4+3
    #pragma unroll
    for (int r=0;r<32;r++){
      float4 a = stile[r][h4];
      acc[r].x += a.x*b0.x + a.y*b0.z + a.z*b1.x + a.w*b1.z;
      acc[r].y += a.x*b0.y + a.y*b0.w + a.z*b1.y + a.w*b1.w;
    }
  }
  #pragma unroll
  for (int r=0;r<32;r++){
    BuRe[(size_t)(l0+r)*P + p] = acc[r].x;
    BuIm[(size_t)(l0+r)*P + p] = acc[r].y;
  }
}

// ---------------- Kernel 2: per-chunk local scan finals (zero init) ----------------
__global__ __launch_bounds__(256) void scan_finals(const float* __restrict__ BuRe,
                                                   const float* __restrict__ BuIm,
                                                   const float* __restrict__ A_diag,
                                                   const float* __restrict__ steps,
                                                   float* __restrict__ finals){
  int p = threadIdx.x;
  int c = blockIdx.x;
  int part = blockIdx.y;
  const float* Bu = part ? BuIm : BuRe;
  Params q = get_params(A_diag, steps, p);
  float x1 = 0.f, x2 = 0.f;
  const float* bp = Bu + (size_t)c*CL*P + p;
  #pragma unroll 4
  for (int i=0;i<CL;i++){
    float u = bp[(size_t)i*P];
    float n1 = q.M11*x1 + q.M12*x2 + q.s1*u;
    float n2 = q.M21*x1 + q.M22*x2 + q.s2*u;
    x1 = n1; x2 = n2;
  }
  ((float2*)finals)[(size_t)(part*NCH + c)*P + p] = make_float2(x1,x2);
}

// ---------------- Kernel 3: sequential combine over chunks -> initial carries ----------------
__global__ __launch_bounds__(512) void scan_inits(const float* __restrict__ A_diag,
                                                  const float* __restrict__ steps,
                                                  const float* __restrict__ finals,
                                                  float* __restrict__ inits){
  int tid = threadIdx.x;
  int p = tid & (P-1);
  int part = tid >> 8;
  Params q = get_params(A_diag, steps, p);
  // Mpow = M^CL via log2(CL)=6 squarings
  float a=q.M11, b=q.M12, c=q.M21, d=q.M22;
  #pragma unroll
  for (int s=0;s<6;s++){
    float na = a*a + b*c;
    float nb = a*b + b*d;
    float nc = c*a + d*c;
    float nd = c*b + d*d;
    a=na; b=nb; c=nc; d=nd;
  }
  const float2* f2 = (const float2*)finals;
  float2* i2 = (float2*)inits;
  float x1=0.f, x2=0.f;
  for (int ch=0; ch<NCH; ch++){
    size_t idx = (size_t)(part*NCH + ch)*P + p;
    i2[idx] = make_float2(x1,x2);
    float2 f = f2[idx];
    float n1 = a*x1 + b*x2 + f.x;
    float n2 = c*x1 + d*x2 + f.y;
    x1 = n1; x2 = n2;
  }
}

// ---------------- Kernel 4: re-scan with carries, write x2 in-place over Bu ----------------
__global__ __launch_bounds__(256) void scan_emit(float* __restrict__ BuRe,
                                                 float* __restrict__ BuIm,
                                                 const float* __restrict__ A_diag,
                                                 const float* __restrict__ steps,
                                                 const float* __restrict__ inits){
  int p = threadIdx.x;
  int c = blockIdx.x;
  int part = blockIdx.y;
  float* Bu = part ? BuIm : BuRe;
  Params q = get_params(A_diag, steps, p);
  float2 iv = ((const float2*)inits)[(size_t)(part*NCH + c)*P + p];
  float x1 = iv.x, x2 = iv.y;
  float* bp = Bu + (size_t)c*CL*P + p;
  #pragma unroll 4
  for (int i=0;i<CL;i++){
    float u = bp[(size_t)i*P];
    float n1 = q.M11*x1 + q.M12*x2 + q.s1*u;
    float n2 = q.M21*x1 + q.M22*x2 + q.s2*u;
    x1 = n1; x2 = n2;
    bp[(size_t)i*P] = x2;                 // overwrite Bu with scan result x2
  }
}

// ---------------- Kernel 5: ys = Re(x2 @ Cc.T) + input*D ----------------
// block: 256 threads (h=tid&127, row-half=tid>>7), 16 l-rows per block.
__global__ __launch_bounds__(256) void out_gemm(const float* __restrict__ x2re,
                                                const float* __restrict__ x2im,
                                                const float* __restrict__ Cw,
                                                const float* __restrict__ Dv,
                                                const float* __restrict__ in,
                                                float* __restrict__ out){
  __shared__ float4 sRe[16][64];          // 16 rows x 256 p (as float4) = 16KB
  __shared__ float4 sIm[16][64];
  int l0 = blockIdx.x * 16;
  const float4* gre = (const float4*)(x2re + (size_t)l0*P);
  const float4* gim = (const float4*)(x2im + (size_t)l0*P);
  for (int i = threadIdx.x; i < 16*64; i += 256){
    sRe[i>>6][i&63] = gre[i];
    sIm[i>>6][i&63] = gim[i];
  }
  __syncthreads();
  int h  = threadIdx.x & 127;
  int rs = threadIdx.x >> 7;              // 0/1 -> rows rs*8 .. rs*8+7
  const float4* C4 = (const float4*)(Cw + (size_t)h*P*2); // C[h][p][{re,im}] -> 128 float4
  float acc[8];
  #pragma unroll
  for (int r=0;r<8;r++) acc[r]=0.f;
  for (int p4=0; p4<64; p4++){
    float4 c0 = C4[p4*2];                 // p=4p4: re,im ; p=4p4+1: re,im
    float4 c1 = C4[p4*2+1];
    #pragma unroll
    for (int r=0;r<8;r++){
      float4 xr = sRe[rs*8+r][p4];
      float4 xi = sIm[rs*8+r][p4];
      acc[r] += xr.x*c0.x - xi.x*c0.y + xr.y*c0.z - xi.y*c0.w
              + xr.z*c1.x - xi.z*c1.y + xr.w*c1.z - xi.w*c1.w;
    }
  }
  float dv = Dv[h];
  #pragma unroll
  for (int r=0;r<8;r++){
    int l = l0 + rs*8 + r;
    out[(size_t)l*H + h] = acc[r] + in[(size_t)l*H + h]*dv;
  }
}

extern "C" void kernel_launch(void* const* d_in, const int* in_sizes, int n_in,
                              void* d_out, int out_size, void* d_ws, size_t ws_size,
                              hipStream_t stream) {
  const float* in     = (const float*)d_in[0];   // (L,H)
  const float* A_diag = (const float*)d_in[1];   // (P,)
  const float* B      = (const float*)d_in[2];   // (P,H,2)
  const float* Cw     = (const float*)d_in[3];   // (H,P,2)
  const float* Dv     = (const float*)d_in[4];   // (H,)
  const float* steps  = (const float*)d_in[5];   // (P,)
  float* out = (float*)d_out;

  float* ws = (float*)d_ws;
  float* BuRe   = ws;                                  // L*P floats (16MB)
  float* BuIm   = ws + (size_t)L*P;                    // L*P floats
  float* finals = ws + 2*(size_t)L*P;                  // 2*NCH*P*2 floats (1MB)
  float* inits  = finals + (size_t)2*NCH*P*2;          // 2*NCH*P*2 floats

  bu_gemm<<<L/32, 256, 0, stream>>>(in, B, BuRe, BuIm);
  scan_finals<<<dim3(NCH,2), 256, 0, stream>>>(BuRe, BuIm, A_diag, steps, finals);
  scan_inits<<<1, 512, 0, stream>>>(A_diag, steps, finals, inits);
  scan_emit<<<dim3(NCH,2), 256, 0, stream>>>(BuRe, BuIm, A_diag, steps, inits);
  out_gemm<<<L/16, 256, 0, stream>>>(BuRe, BuIm, Cw, Dv, in, out);
}